// Round 2
// baseline (881.515 us; speedup 1.0000x reference)
//
#include <hip/hip_runtime.h>

typedef __bf16 bf16x8 __attribute__((ext_vector_type(8)));
typedef __bf16 bf16x4 __attribute__((ext_vector_type(4)));
typedef float f32x4 __attribute__((ext_vector_type(4)));

// Convert the four 128x128 fp32 weight matrices to bf16 in workspace.
// Layout: Wq @ 0, Wk @ 16384, Wv @ 32768, Wo @ 49152 (elements).
__global__ __launch_bounds__(256) void wcvt(const float* __restrict__ Wq,
                                            const float* __restrict__ Wk,
                                            const float* __restrict__ Wv,
                                            const float* __restrict__ Wo,
                                            __bf16* __restrict__ dst) {
  int i = blockIdx.x * 256 + threadIdx.x;    // 0..16383
  dst[i]          = (__bf16)Wq[i];
  dst[16384 + i]  = (__bf16)Wk[i];
  dst[32768 + i]  = (__bf16)Wv[i];
  dst[49152 + i]  = (__bf16)Wo[i];
}

// One block per node. 384 threads = 6 waves. Wave w owns rows 16w..16w+15.
// LDS = 41984 B -> 3 blocks/CU; launch_bounds(384,5) caps VGPR at 102 so
// 18 waves/CU can schedule.
__global__ __launch_bounds__(384, 5) void attn_kernel(
    const float* __restrict__ x, const float* __restrict__ bk,
    const float* __restrict__ bv, const float* __restrict__ bo,
    const __bf16* __restrict__ Wbf, float* __restrict__ out) {
  // all strides are 16B-aligned and give <=2-way bank aliasing (free):
  // 40 shorts = 20 words (gcd(20,32)=4 -> 8 banks), 104 shorts = 52 words (gcd 4).
  __shared__ __bf16 Qs[96 * 40];    // Q_h (96 x 32); aliased as O_h after phase B
  __shared__ __bf16 Ks[96 * 40];    // K_h
  __shared__ __bf16 Vts[32 * 104];  // V_h transposed: Vt[d][t]
  __shared__ __bf16 Pas[96 * 104];  // P[q][k]

  const int tid  = threadIdx.x;
  const int wid  = tid >> 6;      // 0..5
  const int lane = tid & 63;
  const int quad = lane >> 4;     // 0..3
  const int l16  = lane & 15;
  const int node = blockIdx.x;

  f32x4 accO[8];
  #pragma unroll
  for (int i = 0; i < 8; ++i) accO[i] = (f32x4){0.f, 0.f, 0.f, 0.f};

  // QKV ownership: waves (0,1)->Q, (2,3)->K, (4,5)->V; even wave: mt 0..2, odd: 3..5
  const int mat = wid >> 1;
  const int mt0 = (wid & 1) * 3;
  const __bf16* Wmat  = Wbf + mat * 16384;
  const __bf16* Wo_bf = Wbf + 3 * 16384;
  const float*  xbase = x + (size_t)node * (96 * 128);

  for (int h = 0; h < 4; ++h) {
    // ---- Phase A: {Q,K,V}_h = x @ W.T (+bias; bq cancels in softmax-over-q) ----
    // A-fragments read directly from global fp32 (L1/L2-cached re-reads).
    float bias0 = 0.f, bias1 = 0.f;
    if (mat == 1)      { bias0 = bk[h * 32 + l16]; bias1 = bk[h * 32 + 16 + l16]; }
    else if (mat == 2) { bias0 = bv[h * 32 + l16]; bias1 = bv[h * 32 + 16 + l16]; }

    #pragma unroll
    for (int m = 0; m < 3; ++m) {
      int mt = mt0 + m;
      const float* xr = xbase + (mt * 16 + l16) * 128 + quad * 8;
      f32x4 a0 = {0,0,0,0}, a1 = {0,0,0,0};
      #pragma unroll
      for (int ks = 0; ks < 4; ++ks) {
        float4 u = *(const float4*)(xr + ks * 32);
        float4 v = *(const float4*)(xr + ks * 32 + 4);
        bf16x8 afr;
        afr[0] = (__bf16)u.x; afr[1] = (__bf16)u.y;
        afr[2] = (__bf16)u.z; afr[3] = (__bf16)u.w;
        afr[4] = (__bf16)v.x; afr[5] = (__bf16)v.y;
        afr[6] = (__bf16)v.z; afr[7] = (__bf16)v.w;
        bf16x8 b0 = *(const bf16x8*)(Wmat + (h * 32 + l16) * 128 + ks * 32 + quad * 8);
        bf16x8 b1 = *(const bf16x8*)(Wmat + (h * 32 + 16 + l16) * 128 + ks * 32 + quad * 8);
        a0 = __builtin_amdgcn_mfma_f32_16x16x32_bf16(afr, b0, a0, 0, 0, 0);
        a1 = __builtin_amdgcn_mfma_f32_16x16x32_bf16(afr, b1, a1, 0, 0, 0);
      }
      if (mat == 0) {
        #pragma unroll
        for (int r = 0; r < 4; ++r) {
          Qs[(mt * 16 + quad * 4 + r) * 40 + l16]      = (__bf16)a0[r];
          Qs[(mt * 16 + quad * 4 + r) * 40 + 16 + l16] = (__bf16)a1[r];
        }
      } else if (mat == 1) {
        #pragma unroll
        for (int r = 0; r < 4; ++r) {
          Ks[(mt * 16 + quad * 4 + r) * 40 + l16]      = (__bf16)(a0[r] + bias0);
          Ks[(mt * 16 + quad * 4 + r) * 40 + 16 + l16] = (__bf16)(a1[r] + bias1);
        }
      } else {
        bf16x4 v0 = { (__bf16)(a0[0] + bias0), (__bf16)(a0[1] + bias0),
                      (__bf16)(a0[2] + bias0), (__bf16)(a0[3] + bias0) };
        bf16x4 v1 = { (__bf16)(a1[0] + bias1), (__bf16)(a1[1] + bias1),
                      (__bf16)(a1[2] + bias1), (__bf16)(a1[3] + bias1) };
        *(bf16x4*)&Vts[l16 * 104        + mt * 16 + quad * 4] = v0;
        *(bf16x4*)&Vts[(16 + l16) * 104 + mt * 16 + quad * 4] = v1;
      }
    }
    __syncthreads();

    // ---- Phase B: S' = K_h @ Q_h^T (row = k, col = q); softmax over q = row-wise ----
    bf16x8 ak = *(const bf16x8*)&Ks[(wid * 16 + l16) * 40 + quad * 8];
    f32x4 s[6];
    #pragma unroll
    for (int qt = 0; qt < 6; ++qt) {
      bf16x8 bq8 = *(const bf16x8*)&Qs[(qt * 16 + l16) * 40 + quad * 8];
      f32x4 z = {0,0,0,0};
      s[qt] = __builtin_amdgcn_mfma_f32_16x16x32_bf16(ak, bq8, z, 0, 0, 0);
    }
    const float SC = 0.17677669529663687f * 1.4426950408889634f; // (1/sqrt32)*log2e
    float rinv[4];
    #pragma unroll
    for (int r = 0; r < 4; ++r) {
      float mval = s[0][r];
      #pragma unroll
      for (int qt = 1; qt < 6; ++qt) mval = fmaxf(mval, s[qt][r]);
      #pragma unroll
      for (int d = 1; d < 16; d <<= 1) mval = fmaxf(mval, __shfl_xor(mval, d, 64));
      float sum = 0.f;
      #pragma unroll
      for (int qt = 0; qt < 6; ++qt) {
        float e = exp2f((s[qt][r] - mval) * SC);
        s[qt][r] = e;
        sum += e;
      }
      #pragma unroll
      for (int d = 1; d < 16; d <<= 1) sum += __shfl_xor(sum, d, 64);
      rinv[r] = 1.f / sum;
    }
    // write P[q][k]; wave w owns k-columns 16w..16w+15; packed 4-wide along k
    #pragma unroll
    for (int qt = 0; qt < 6; ++qt) {
      bf16x4 pv = { (__bf16)(s[qt][0] * rinv[0]), (__bf16)(s[qt][1] * rinv[1]),
                    (__bf16)(s[qt][2] * rinv[2]), (__bf16)(s[qt][3] * rinv[3]) };
      *(bf16x4*)&Pas[(qt * 16 + l16) * 104 + wid * 16 + quad * 4] = pv;
    }
    __syncthreads();

    // ---- Phase C: O_h = P @ V ----
    #pragma unroll
    for (int nt = 0; nt < 2; ++nt) {
      f32x4 acc = {0,0,0,0};
      #pragma unroll
      for (int ks = 0; ks < 3; ++ks) {
        bf16x8 ap  = *(const bf16x8*)&Pas[(wid * 16 + l16) * 104 + ks * 32 + quad * 8];
        bf16x8 bv8 = *(const bf16x8*)&Vts[(nt * 16 + l16) * 104 + ks * 32 + quad * 8];
        acc = __builtin_amdgcn_mfma_f32_16x16x32_bf16(ap, bv8, acc, 0, 0, 0);
      }
      #pragma unroll
      for (int r = 0; r < 4; ++r)   // O_h aliases Qs (Q_h dead after phase B)
        Qs[(wid * 16 + quad * 4 + r) * 40 + nt * 16 + l16] = (__bf16)acc[r];
    }
    // no barrier: phase D reads only this wave's own O_h rows

    // ---- Phase D: out += O_h @ Wo.T[:, h*32:(h+1)*32] ----
    bf16x8 ao = *(const bf16x8*)&Qs[(wid * 16 + l16) * 40 + quad * 8];
    #pragma unroll
    for (int nt = 0; nt < 8; ++nt) {
      bf16x8 bw = *(const bf16x8*)(Wo_bf + (nt * 16 + l16) * 128 + h * 32 + quad * 8);
      accO[nt] = __builtin_amdgcn_mfma_f32_16x16x32_bf16(ao, bw, accO[nt], 0, 0, 0);
    }
    __syncthreads();   // protect Qs/Ks/Vts/Pas reuse by next head
  }

  // ---- epilogue: add bo, store fp32 (lanes of a quad cover 64B contiguous) ----
  float* ob = out + (size_t)node * (96 * 128);
  #pragma unroll
  for (int nt = 0; nt < 8; ++nt) {
    int col = nt * 16 + l16;
    float bias = bo[col];
    #pragma unroll
    for (int r = 0; r < 4; ++r) {
      int row = wid * 16 + quad * 4 + r;
      ob[row * 128 + col] = accO[nt][r] + bias;
    }
  }
}

extern "C" void kernel_launch(void* const* d_in, const int* in_sizes, int n_in,
                              void* d_out, int out_size, void* d_ws, size_t ws_size,
                              hipStream_t stream) {
  const float* x  = (const float*)d_in[0];
  const float* Wq = (const float*)d_in[1];
  // d_in[2] = bq: cancels in softmax over the query axis
  const float* Wk = (const float*)d_in[3];
  const float* bk = (const float*)d_in[4];
  const float* Wv = (const float*)d_in[5];
  const float* bv = (const float*)d_in[6];
  const float* Wo = (const float*)d_in[7];
  const float* bo = (const float*)d_in[8];
  int B_N = in_sizes[0] / (96 * 128);        // 4096

  __bf16* Wbf = (__bf16*)d_ws;               // 4 * 16384 bf16 = 128 KiB
  wcvt<<<64, 256, 0, stream>>>(Wq, Wk, Wv, Wo, Wbf);
  attn_kernel<<<B_N, 384, 0, stream>>>(x, bk, bv, bo, Wbf, (float*)d_out);
}